// Round 10
// baseline (79.929 us; speedup 1.0000x reference)
//
#include <hip/hip_runtime.h>

// Problem constants (match reference setup_inputs)
#define B_     128
#define N_     32768
#define DMAX_  16
#define ND_    8
#define NDX_   4
#define BN_    (B_ * N_)          // 4,194,304 elements per plane
#define NKEY   (ND_ + NDX_)       // 12 delay-copy tasks
#define CHUNKS (BN_ / 4)          // 1,048,576 float4 chunks per plane
#define BLOCK  256
#define UNROLL 8
#define TILE   (BLOCK * UNROLL)   // 2048 chunks per block
#define GX     (CHUNKS / TILE)    // 512 blocks per plane-slice

typedef float f4 __attribute__((ext_vector_type(4)));

// Output layout: [X (1), Xd (ND_), Xd_xarea (NDX_), new_threshold (1)] x (B,N).
//
// R9 structure, single-variable change: PLAIN write-back stores everywhere
// (was non-temporal). Tests the last untested (load,store) cache-policy
// quadrant at the proven UNROLL=8 / GX=512 occupancy.
//  - task 0: compute X/nt -> plane 0, plane 13, and all delay==0 planes.
//  - task 1..12: delay>0 copies. Leader = earliest task with my delay;
//    leader writes all planes of its group. Others exit (wave-uniform).
// All local arrays statically indexed (rule #20).

__global__ __launch_bounds__(BLOCK) void alif_r10_kernel(
    const float* __restrict__ V,
    const float* __restrict__ threshold,
    const float* __restrict__ alpha,
    const float* __restrict__ amplitude,
    const float* __restrict__ buffer,       // (DMAX_, B, N)
    const int*   __restrict__ delays,       // (ND_,)
    const int*   __restrict__ delays_x,     // (NDX_,)
    float*       __restrict__ out)          // (14, B, N)
{
    const int task  = blockIdx.y;                          // 0..12
    const int cbase = blockIdx.x * TILE + threadIdx.x;     // chunk index base

    // 12 delay keys at compile-time indices (registers/SGPRs, wave-uniform).
    int key[NKEY];
#pragma unroll
    for (int j = 0; j < ND_; ++j)  key[j]       = delays[j];
#pragma unroll
    for (int j = 0; j < NDX_; ++j) key[ND_ + j] = delays_x[j];

    if (task == 0) {
        // Compute X and new_threshold tiles in registers.
        f4 v[UNROLL], th[UNROLL], X[UNROLL], nt[UNROLL];
#pragma unroll
        for (int u = 0; u < UNROLL; ++u) {
            const int e = (cbase + u * BLOCK) * 4;
            v[u]  = *reinterpret_cast<const f4*>(V + e);          // cached
            th[u] = *reinterpret_cast<const f4*>(threshold + e);  // cached
        }
#pragma unroll
        for (int u = 0; u < UNROLL; ++u) {
            const int e = (cbase + u * BLOCK) * 4;
            const int n = e & (N_ - 1);
            const f4 al = *reinterpret_cast<const f4*>(alpha + n);     // L2-hot
            const f4 am = *reinterpret_cast<const f4*>(amplitude + n);
#pragma unroll
            for (int c = 0; c < 4; ++c) {
                X[u][c]  = (v[u][c] - th[u][c] - 1.0f) >= 0.0f ? 1.0f : 0.0f;
                nt[u][c] = th[u][c] * al[c] + X[u][c] * am[c];
            }
        }
        // Stores grouped per destination plane (burst-coherent streams).
#pragma unroll
        for (int u = 0; u < UNROLL; ++u) {
            const int e = (cbase + u * BLOCK) * 4;
            *reinterpret_cast<f4*>(out + e) = X[u];
        }
#pragma unroll
        for (int p = 0; p < NKEY; ++p) {
            if (key[p] == 0) {              // delay-0 planes duplicate X
                float* dst = out + (size_t)(1 + p) * BN_;
#pragma unroll
                for (int u = 0; u < UNROLL; ++u) {
                    const int e = (cbase + u * BLOCK) * 4;
                    *reinterpret_cast<f4*>(dst + e) = X[u];
                }
            }
        }
#pragma unroll
        for (int u = 0; u < UNROLL; ++u) {
            const int e = (cbase + u * BLOCK) * 4;
            *reinterpret_cast<f4*>(out + (size_t)13 * BN_ + e) = nt[u];
        }
        return;
    }

    const int t = task - 1;                 // my index in key[], 0..11 (runtime)

    // My delay via unrolled select chain (no dynamic local indexing).
    int myd = 0;
#pragma unroll
    for (int u = 0; u < NKEY; ++u)
        if (u == t) myd = key[u];

    if (myd == 0) return;                   // task 0 owns delay-0 planes

    // Leader = earliest task with this delay; non-leaders exit (wave-uniform).
#pragma unroll
    for (int u = 0; u < NKEY; ++u)
        if (u < t && key[u] == myd) return;

    // Load the group's source tile once (8 independent cached loads).
    const float* src = buffer + (size_t)(myd - 1) * BN_;
    f4 val[UNROLL];
#pragma unroll
    for (int u = 0; u < UNROLL; ++u) {
        const int e = (cbase + u * BLOCK) * 4;
        val[u] = *reinterpret_cast<const f4*>(src + e);
    }

    // Write every plane in my equal-delay group, plane-by-plane.
#pragma unroll
    for (int p = 0; p < NKEY; ++p) {
        if (p == t || (p > t && key[p] == myd)) {
            float* dst = out + (size_t)(1 + p) * BN_;
#pragma unroll
            for (int u = 0; u < UNROLL; ++u) {
                const int e = (cbase + u * BLOCK) * 4;
                *reinterpret_cast<f4*>(dst + e) = val[u];
            }
        }
    }
}

extern "C" void kernel_launch(void* const* d_in, const int* in_sizes, int n_in,
                              void* d_out, int out_size, void* d_ws, size_t ws_size,
                              hipStream_t stream) {
    const float* V         = (const float*)d_in[0];
    const float* threshold = (const float*)d_in[1];
    const float* alpha     = (const float*)d_in[2];
    const float* amplitude = (const float*)d_in[3];
    const float* buffer    = (const float*)d_in[4];
    const int*   delays    = (const int*)d_in[5];
    const int*   delays_x  = (const int*)d_in[6];
    float*       out       = (float*)d_out;

    dim3 grid(GX, 1 + NKEY);                // (512, 13)
    alif_r10_kernel<<<grid, dim3(BLOCK), 0, stream>>>(
        V, threshold, alpha, amplitude, buffer, delays, delays_x, out);
}

// Round 11
// 70.798 us; speedup vs baseline: 1.1290x; 1.1290x over previous
//
#include <hip/hip_runtime.h>

// Problem constants (match reference setup_inputs)
#define B_     128
#define N_     32768
#define DMAX_  16
#define ND_    8
#define NDX_   4
#define BN_    (B_ * N_)          // 4,194,304 elements per plane
#define NKEY   (ND_ + NDX_)       // 12 delay-copy tasks
#define CHUNKS (BN_ / 4)          // 1,048,576 float4 chunks per plane
#define BLOCK  256
#define UNROLL 8
#define TILE   (BLOCK * UNROLL)   // 2048 chunks per block
#define GX     (CHUNKS / TILE)    // 512 blocks per plane-slice

typedef float f4 __attribute__((ext_vector_type(4)));

// Output layout: [X (1), Xd (ND_), Xd_xarea (NDX_), new_threshold (1)] x (B,N).
//
// R9 structure, single-variable change: NON-TEMPORAL loads on all streaming
// inputs (V, threshold, buffer) — completes the (load,store) policy matrix
// at the proven UNROLL=8 / GX=512 occupancy. nt stores kept (R10 showed
// plain stores cost +16 us). alpha/amplitude stay cached (tiny, reused).
//  - task 0: compute X/nt -> plane 0, plane 13, and all delay==0 planes.
//  - task 1..12: delay>0 copies. Leader = earliest task with my delay;
//    leader writes all planes of its group. Others exit (wave-uniform).
// All local arrays statically indexed (rule #20).

__global__ __launch_bounds__(BLOCK) void alif_r11_kernel(
    const float* __restrict__ V,
    const float* __restrict__ threshold,
    const float* __restrict__ alpha,
    const float* __restrict__ amplitude,
    const float* __restrict__ buffer,       // (DMAX_, B, N)
    const int*   __restrict__ delays,       // (ND_,)
    const int*   __restrict__ delays_x,     // (NDX_,)
    float*       __restrict__ out)          // (14, B, N)
{
    const int task  = blockIdx.y;                          // 0..12
    const int cbase = blockIdx.x * TILE + threadIdx.x;     // chunk index base

    // 12 delay keys at compile-time indices (registers/SGPRs, wave-uniform).
    int key[NKEY];
#pragma unroll
    for (int j = 0; j < ND_; ++j)  key[j]       = delays[j];
#pragma unroll
    for (int j = 0; j < NDX_; ++j) key[ND_ + j] = delays_x[j];

    if (task == 0) {
        // Compute X and new_threshold tiles in registers.
        f4 v[UNROLL], th[UNROLL], X[UNROLL], nt[UNROLL];
#pragma unroll
        for (int u = 0; u < UNROLL; ++u) {
            const int e = (cbase + u * BLOCK) * 4;
            v[u]  = __builtin_nontemporal_load(reinterpret_cast<const f4*>(V + e));
            th[u] = __builtin_nontemporal_load(reinterpret_cast<const f4*>(threshold + e));
        }
#pragma unroll
        for (int u = 0; u < UNROLL; ++u) {
            const int e = (cbase + u * BLOCK) * 4;
            const int n = e & (N_ - 1);
            const f4 al = *reinterpret_cast<const f4*>(alpha + n);     // L2-hot
            const f4 am = *reinterpret_cast<const f4*>(amplitude + n);
#pragma unroll
            for (int c = 0; c < 4; ++c) {
                X[u][c]  = (v[u][c] - th[u][c] - 1.0f) >= 0.0f ? 1.0f : 0.0f;
                nt[u][c] = th[u][c] * al[c] + X[u][c] * am[c];
            }
        }
        // Stores grouped per destination plane (burst-coherent streams).
#pragma unroll
        for (int u = 0; u < UNROLL; ++u) {
            const int e = (cbase + u * BLOCK) * 4;
            __builtin_nontemporal_store(X[u], reinterpret_cast<f4*>(out + e));
        }
#pragma unroll
        for (int p = 0; p < NKEY; ++p) {
            if (key[p] == 0) {              // delay-0 planes duplicate X
                float* dst = out + (size_t)(1 + p) * BN_;
#pragma unroll
                for (int u = 0; u < UNROLL; ++u) {
                    const int e = (cbase + u * BLOCK) * 4;
                    __builtin_nontemporal_store(X[u], reinterpret_cast<f4*>(dst + e));
                }
            }
        }
#pragma unroll
        for (int u = 0; u < UNROLL; ++u) {
            const int e = (cbase + u * BLOCK) * 4;
            __builtin_nontemporal_store(nt[u],
                reinterpret_cast<f4*>(out + (size_t)13 * BN_ + e));
        }
        return;
    }

    const int t = task - 1;                 // my index in key[], 0..11 (runtime)

    // My delay via unrolled select chain (no dynamic local indexing).
    int myd = 0;
#pragma unroll
    for (int u = 0; u < NKEY; ++u)
        if (u == t) myd = key[u];

    if (myd == 0) return;                   // task 0 owns delay-0 planes

    // Leader = earliest task with this delay; non-leaders exit (wave-uniform).
#pragma unroll
    for (int u = 0; u < NKEY; ++u)
        if (u < t && key[u] == myd) return;

    // Load the group's source tile once (8 independent nt loads).
    const float* src = buffer + (size_t)(myd - 1) * BN_;
    f4 val[UNROLL];
#pragma unroll
    for (int u = 0; u < UNROLL; ++u) {
        const int e = (cbase + u * BLOCK) * 4;
        val[u] = __builtin_nontemporal_load(reinterpret_cast<const f4*>(src + e));
    }

    // Write every plane in my equal-delay group, plane-by-plane.
#pragma unroll
    for (int p = 0; p < NKEY; ++p) {
        if (p == t || (p > t && key[p] == myd)) {
            float* dst = out + (size_t)(1 + p) * BN_;
#pragma unroll
            for (int u = 0; u < UNROLL; ++u) {
                const int e = (cbase + u * BLOCK) * 4;
                __builtin_nontemporal_store(val[u], reinterpret_cast<f4*>(dst + e));
            }
        }
    }
}

extern "C" void kernel_launch(void* const* d_in, const int* in_sizes, int n_in,
                              void* d_out, int out_size, void* d_ws, size_t ws_size,
                              hipStream_t stream) {
    const float* V         = (const float*)d_in[0];
    const float* threshold = (const float*)d_in[1];
    const float* alpha     = (const float*)d_in[2];
    const float* amplitude = (const float*)d_in[3];
    const float* buffer    = (const float*)d_in[4];
    const int*   delays    = (const int*)d_in[5];
    const int*   delays_x  = (const int*)d_in[6];
    float*       out       = (float*)d_out;

    dim3 grid(GX, 1 + NKEY);                // (512, 13)
    alif_r11_kernel<<<grid, dim3(BLOCK), 0, stream>>>(
        V, threshold, alpha, amplitude, buffer, delays, delays_x, out);
}

// Round 12
// 63.566 us; speedup vs baseline: 1.2574x; 1.1138x over previous
//
#include <hip/hip_runtime.h>

// Problem constants (match reference setup_inputs)
#define B_     128
#define N_     32768
#define DMAX_  16
#define ND_    8
#define NDX_   4
#define BN_    (B_ * N_)          // 4,194,304 elements per plane
#define NKEY   (ND_ + NDX_)       // 12 delay-copy tasks
#define CHUNKS (BN_ / 4)          // 1,048,576 float4 chunks per plane
#define BLOCK  256
#define UNROLL 8
#define TILE   (BLOCK * UNROLL)   // 2048 chunks per block
#define GX     (CHUNKS / TILE)    // 512 blocks per plane-slice

typedef float f4 __attribute__((ext_vector_type(4)));

// Output layout: [X (1), Xd (ND_), Xd_xarea (NDX_), new_threshold (1)] x (B,N).
//
// FINAL (best measured: 63.3 us, R7): plane-major + leader dedup, UNROLL=8,
// cached loads (MALL keeps the ~90MB input set resident across replays) +
// non-temporal stores (235MB write-once stream must not thrash L2 — plain
// stores cost +16us, R10). Full (load,store) policy matrix measured R6-R11.
//   task 0      : compute X + nt -> planes 0, 13
//   task 1..12  : delay copies. Leader = earliest task with my delay value;
//                 leader loads source once, writes ALL planes of its group.
//                 Non-leaders exit (wave-uniform). delay==0 recomputes X.
// All local arrays statically indexed (rule #20).

__global__ __launch_bounds__(BLOCK) void alif_final_kernel(
    const float* __restrict__ V,
    const float* __restrict__ threshold,
    const float* __restrict__ alpha,
    const float* __restrict__ amplitude,
    const float* __restrict__ buffer,       // (DMAX_, B, N)
    const int*   __restrict__ delays,       // (ND_,)
    const int*   __restrict__ delays_x,     // (NDX_,)
    float*       __restrict__ out)          // (14, B, N)
{
    const int task  = blockIdx.y;                          // 0..12
    const int cbase = blockIdx.x * TILE + threadIdx.x;     // chunk index base

    if (task == 0) {
        // Compute planes: X (plane 0) and new_threshold (plane 13).
        f4 v[UNROLL], th[UNROLL];
#pragma unroll
        for (int u = 0; u < UNROLL; ++u) {
            const int e = (cbase + u * BLOCK) * 4;
            v[u]  = *reinterpret_cast<const f4*>(V + e);          // cached
            th[u] = *reinterpret_cast<const f4*>(threshold + e);  // cached
        }
#pragma unroll
        for (int u = 0; u < UNROLL; ++u) {
            const int e = (cbase + u * BLOCK) * 4;
            const int n = e & (N_ - 1);
            const f4 al = *reinterpret_cast<const f4*>(alpha + n);
            const f4 am = *reinterpret_cast<const f4*>(amplitude + n);
            f4 X, nt;
#pragma unroll
            for (int c = 0; c < 4; ++c) {
                X[c]  = (v[u][c] - th[u][c] - 1.0f) >= 0.0f ? 1.0f : 0.0f;
                nt[c] = th[u][c] * al[c] + X[c] * am[c];
            }
            __builtin_nontemporal_store(X,  reinterpret_cast<f4*>(out + e));
            __builtin_nontemporal_store(nt, reinterpret_cast<f4*>(out + (size_t)13 * BN_ + e));
        }
        return;
    }

    // 12 delay keys at compile-time indices (registers/SGPRs, wave-uniform).
    int key[NKEY];
#pragma unroll
    for (int j = 0; j < ND_; ++j)  key[j]       = delays[j];
#pragma unroll
    for (int j = 0; j < NDX_; ++j) key[ND_ + j] = delays_x[j];

    const int t = task - 1;                 // my index in key[], 0..11 (runtime)

    // My delay via unrolled select chain (no dynamic local indexing).
    int myd = 0;
#pragma unroll
    for (int u = 0; u < NKEY; ++u)
        if (u == t) myd = key[u];

    // Leader = earliest task with this delay; non-leaders exit (wave-uniform).
#pragma unroll
    for (int u = 0; u < NKEY; ++u)
        if (u < t && key[u] == myd) return;

    // Load the group's source tile once (8 independent cached loads).
    f4 val[UNROLL];
    if (myd == 0) {
        // new_buffer[0] == X: recompute from V, threshold (L3-hot).
        f4 v[UNROLL], th[UNROLL];
#pragma unroll
        for (int u = 0; u < UNROLL; ++u) {
            const int e = (cbase + u * BLOCK) * 4;
            v[u]  = *reinterpret_cast<const f4*>(V + e);
            th[u] = *reinterpret_cast<const f4*>(threshold + e);
        }
#pragma unroll
        for (int u = 0; u < UNROLL; ++u)
#pragma unroll
            for (int c = 0; c < 4; ++c)
                val[u][c] = (v[u][c] - th[u][c] - 1.0f) >= 0.0f ? 1.0f : 0.0f;
    } else {
        const float* src = buffer + (size_t)(myd - 1) * BN_;
#pragma unroll
        for (int u = 0; u < UNROLL; ++u) {
            const int e = (cbase + u * BLOCK) * 4;
            val[u] = *reinterpret_cast<const f4*>(src + e);       // cached
        }
    }

    // Write every plane in my equal-delay group, plane-by-plane (nt stores).
#pragma unroll
    for (int p = 0; p < NKEY; ++p) {
        if (p == t || (p > t && key[p] == myd)) {
            float* dst = out + (size_t)(1 + p) * BN_;
#pragma unroll
            for (int u = 0; u < UNROLL; ++u) {
                const int e = (cbase + u * BLOCK) * 4;
                __builtin_nontemporal_store(val[u], reinterpret_cast<f4*>(dst + e));
            }
        }
    }
}

extern "C" void kernel_launch(void* const* d_in, const int* in_sizes, int n_in,
                              void* d_out, int out_size, void* d_ws, size_t ws_size,
                              hipStream_t stream) {
    const float* V         = (const float*)d_in[0];
    const float* threshold = (const float*)d_in[1];
    const float* alpha     = (const float*)d_in[2];
    const float* amplitude = (const float*)d_in[3];
    const float* buffer    = (const float*)d_in[4];
    const int*   delays    = (const int*)d_in[5];
    const int*   delays_x  = (const int*)d_in[6];
    float*       out       = (float*)d_out;

    dim3 grid(GX, 1 + NKEY);                // (512, 13)
    alif_final_kernel<<<grid, dim3(BLOCK), 0, stream>>>(
        V, threshold, alpha, amplitude, buffer, delays, delays_x, out);
}